// Round 2
// baseline (98.918 us; speedup 1.0000x reference)
//
#include <hip/hip_runtime.h>
#include <hip/hip_bf16.h>

typedef __attribute__((ext_vector_type(8))) short short8;
typedef __attribute__((ext_vector_type(4))) float f32x4;

#define NFACE 16384
#define NBATCH 8
#define CIN 128
#define COUT 128
#define KGEMM 512
#define MBLK 32
#define LDF 520   // fcv LDS row stride in bf16 elems: 512 + 8 (16B pad)
#define GRID ((NBATCH * NFACE) / MBLK)   // 4096, divisible by 8

__device__ __forceinline__ unsigned short f2bf(float x) {
    union { float f; unsigned u; } v; v.f = x;
    unsigned r = v.u + 0x7fffu + ((v.u >> 16) & 1u);  // RNE
    return (unsigned short)(r >> 16);
}
__device__ __forceinline__ unsigned pack2bf(float lo, float hi) {
    return (unsigned)f2bf(lo) | ((unsigned)f2bf(hi) << 16);
}
__device__ __forceinline__ float bf_lo(unsigned u) { union { unsigned u; float f; } v; v.u = u << 16; return v.f; }
__device__ __forceinline__ float bf_hi(unsigned u) { union { unsigned u; float f; } v; v.u = u & 0xffff0000u; return v.f; }

// ---- features fp32 -> packed bf16 (uint = 2 channels) ----
__global__ void fconv_kernel(const float* __restrict__ f, unsigned* __restrict__ o, int n4) {
    int i = blockIdx.x * 256 + threadIdx.x;  // one uint4 (8 floats) per thread
    if (i >= n4) return;
    const float4* fp = (const float4*)f;
    float4 a = fp[i * 2], b = fp[i * 2 + 1];
    uint4 r;
    r.x = pack2bf(a.x, a.y); r.y = pack2bf(a.z, a.w);
    r.z = pack2bf(b.x, b.y); r.w = pack2bf(b.z, b.w);
    ((uint4*)o)[i] = r;
}

// ---- weight (OUT_C, C, 1, 4) fp32 -> Bt[o][kk*128 + c] bf16 ----
__global__ void wconv_kernel(const float* __restrict__ w, unsigned short* __restrict__ bt) {
    int i = blockIdx.x * 256 + threadIdx.x;
    if (i >= COUT * CIN) return;
    int o = i >> 7, c = i & 127;
#pragma unroll
    for (int kk = 0; kk < 4; ++kk)
        bt[o * KGEMM + kk * CIN + c] = f2bf(w[(o * CIN + c) * 4 + kk]);
}

template <bool BF16FEAT>
__global__ __launch_bounds__(256, 4)
void meshconv_kernel(const void* __restrict__ featv,
                     const int* __restrict__ ring,
                     const unsigned short* __restrict__ wbt,
                     const float* __restrict__ bias,
                     float* __restrict__ out)
{
    __shared__ unsigned short fcv[MBLK * LDF];
    __shared__ int ridx[MBLK * 6];

    const int t = threadIdx.x;
    // batch-per-XCD swizzle: XCD x gets blocks [x*512, (x+1)*512) = batch x
    const int bid = (blockIdx.x & 7) * (GRID / 8) + (blockIdx.x >> 3);
    const int base = bid * MBLK;
    const int batch = base >> 14;

    for (int i = t; i < MBLK * 6; i += 256)
        ridx[i] = ring[(size_t)base * 6 + i];
    __syncthreads();

    // ---- phase 1: build fcv tile (32 faces x [4 x 128]) in LDS as bf16 ----
    {
        const int c2 = t & 63;   // channel pair {2c2, 2c2+1}
        const int fq = t >> 6;   // 4 faces in flight
        for (int it = 0; it < MBLK / 4; ++it) {
            const int fl = it * 4 + fq;
            const int* ri = &ridx[fl * 6];
            float nl[6], nh[6];
            unsigned u0;
            if (BF16FEAT) {
                const unsigned* fbu = (const unsigned*)featv + (size_t)batch * NFACE * 64;
#pragma unroll
                for (int j = 0; j < 6; ++j) {
                    unsigned u = fbu[(size_t)ri[j] * 64 + c2];
                    if (j == 0) u0 = u;
                    nl[j] = bf_lo(u); nh[j] = bf_hi(u);
                }
            } else {
                const float2* fb = (const float2*)featv + (size_t)batch * NFACE * 64;
#pragma unroll
                for (int j = 0; j < 6; ++j) {
                    float2 u = fb[(size_t)ri[j] * 64 + c2];
                    nl[j] = u.x; nh[j] = u.y;
                }
                u0 = pack2bf(nl[0], nh[0]);
            }

            float fc1l = nl[1] + nl[2] + nl[3] + nl[4] + nl[5];
            float fc1h = nh[1] + nh[2] + nh[3] + nh[4] + nh[5];
            float fc2l = fabsf(5.0f * nl[0] - fc1l);
            float fc2h = fabsf(5.0f * nh[0] - fc1h);
            float fc3l = 0.f, fc3h = 0.f;
#pragma unroll
            for (int a = 1; a < 5; ++a)
#pragma unroll
                for (int b = a + 1; b < 6; ++b) {
                    fc3l += fabsf(nl[a] - nl[b]);
                    fc3h += fabsf(nh[a] - nh[b]);
                }

            unsigned* row = (unsigned*)&fcv[fl * LDF];
            row[c2]        = u0;
            row[64 + c2]   = pack2bf(fc1l, fc1h);
            row[128 + c2]  = pack2bf(fc2l, fc2h);
            row[192 + c2]  = pack2bf(fc3l, fc3h);
        }
    }
    __syncthreads();

    // ---- phase 2: MFMA GEMM  [32 x 512] x [512 x 128] ----
    const int w  = t >> 6;   // wave 0..3 -> cols [32w, 32w+32)
    const int l  = t & 63;
    const int lo = l & 15;
    const int hi = l >> 4;
    const int col0 = w * 32;

    f32x4 acc[2][2];
#pragma unroll
    for (int rt = 0; rt < 2; ++rt)
#pragma unroll
        for (int ct = 0; ct < 2; ++ct)
            acc[rt][ct] = (f32x4){0.f, 0.f, 0.f, 0.f};

    const unsigned short* __restrict__ wb0 = wbt + (size_t)(col0 + lo) * KGEMM;

    for (int ks = 0; ks < 16; ++ks) {
        const int k0 = ks * 32 + hi * 8;
        short8 a0 = *(const short8*)&fcv[(0 * 16 + lo) * LDF + k0];
        short8 a1 = *(const short8*)&fcv[(1 * 16 + lo) * LDF + k0];
        short8 b0 = *(const short8*)&wb0[k0];
        short8 b1 = *(const short8*)&wb0[16 * KGEMM + k0];

        acc[0][0] = __builtin_amdgcn_mfma_f32_16x16x32_bf16(a0, b0, acc[0][0], 0, 0, 0);
        acc[1][0] = __builtin_amdgcn_mfma_f32_16x16x32_bf16(a1, b0, acc[1][0], 0, 0, 0);
        acc[0][1] = __builtin_amdgcn_mfma_f32_16x16x32_bf16(a0, b1, acc[0][1], 0, 0, 0);
        acc[1][1] = __builtin_amdgcn_mfma_f32_16x16x32_bf16(a1, b1, acc[1][1], 0, 0, 0);
    }

    // ---- epilogue: + bias, store fp32 ----
    const float bo0 = bias[col0 + lo];
    const float bo1 = bias[col0 + 16 + lo];
#pragma unroll
    for (int rt = 0; rt < 2; ++rt) {
#pragma unroll
        for (int v = 0; v < 4; ++v) {
            const int r = base + rt * 16 + hi * 4 + v;  // C/D: row=(l>>4)*4+v, col=l&15  [m89]
            out[(size_t)r * COUT + col0 + lo]      = acc[rt][0][v] + bo0;
            out[(size_t)r * COUT + col0 + 16 + lo] = acc[rt][1][v] + bo1;
        }
    }
}

__global__ void zero_kernel(const int* __restrict__ zm, const int* __restrict__ zf,
                            float* __restrict__ out) {
    const int i = blockIdx.x;
    const size_t face = (size_t)zm[i] * NFACE + zf[i];
    out[face * COUT + threadIdx.x] = 0.0f;
}

extern "C" void kernel_launch(void* const* d_in, const int* in_sizes, int n_in,
                              void* d_out, int out_size, void* d_ws, size_t ws_size,
                              hipStream_t stream) {
    const float* feat = (const float*)d_in[0];
    const int*   ring = (const int*)d_in[1];
    const float* wgt  = (const float*)d_in[2];
    const float* bias = (const float*)d_in[3];
    const int*   zm   = (const int*)d_in[4];
    const int*   zf   = (const int*)d_in[5];
    float* out = (float*)d_out;

    const size_t featbf_bytes = (size_t)NBATCH * NFACE * CIN * 2;  // 32 MiB
    const size_t wbt_bytes = (size_t)COUT * KGEMM * 2;             // 128 KiB
    const bool use_bf16 = ws_size >= featbf_bytes + wbt_bytes;

    if (use_bf16) {
        unsigned* featbf = (unsigned*)d_ws;
        unsigned short* wbt = (unsigned short*)((char*)d_ws + featbf_bytes);
        const int n4 = NBATCH * NFACE * CIN / 8;  // uint4 per thread
        hipLaunchKernelGGL(fconv_kernel, dim3((n4 + 255) / 256), dim3(256), 0, stream,
                           feat, featbf, n4);
        hipLaunchKernelGGL(wconv_kernel, dim3((COUT * CIN + 255) / 256), dim3(256), 0, stream,
                           wgt, wbt);
        hipLaunchKernelGGL((meshconv_kernel<true>), dim3(GRID), dim3(256), 0, stream,
                           (const void*)featbf, ring, wbt, bias, out);
    } else {
        unsigned short* wbt = (unsigned short*)d_ws;
        hipLaunchKernelGGL(wconv_kernel, dim3((COUT * CIN + 255) / 256), dim3(256), 0, stream,
                           wgt, wbt);
        hipLaunchKernelGGL((meshconv_kernel<false>), dim3(GRID), dim3(256), 0, stream,
                           (const void*)feat, ring, wbt, bias, out);
    }
    hipLaunchKernelGGL(zero_kernel, dim3(1024), dim3(128), 0, stream, zm, zf, out);
}

// Round 3
// 96.365 us; speedup vs baseline: 1.0265x; 1.0265x over previous
//
#include <hip/hip_runtime.h>
#include <hip/hip_bf16.h>

typedef __attribute__((ext_vector_type(8))) short short8;
typedef __attribute__((ext_vector_type(4))) float f32x4;

#define NFACE 16384
#define NBATCH 8
#define CIN 128
#define COUT 128
#define KGEMM 512
#define MBLK 32
#define LDF 520   // fcv LDS row stride in bf16 elems: 512 + 8 (16B pad)
#define GRID ((NBATCH * NFACE) / MBLK)   // 4096, divisible by 8

__device__ __forceinline__ unsigned short f2bf(float x) {
    union { float f; unsigned u; } v; v.f = x;
    unsigned r = v.u + 0x7fffu + ((v.u >> 16) & 1u);  // RNE
    return (unsigned short)(r >> 16);
}
__device__ __forceinline__ unsigned pack2bf(float lo, float hi) {
    return (unsigned)f2bf(lo) | ((unsigned)f2bf(hi) << 16);
}
__device__ __forceinline__ float bf_lo(unsigned u) { union { unsigned u; float f; } v; v.u = u << 16; return v.f; }
__device__ __forceinline__ float bf_hi(unsigned u) { union { unsigned u; float f; } v; v.u = u & 0xffff0000u; return v.f; }

// ---- features fp32 -> packed bf16 (uint = 2 channels) ----
__global__ void fconv_kernel(const float* __restrict__ f, unsigned* __restrict__ o, int n4) {
    int i = blockIdx.x * 256 + threadIdx.x;  // one uint4 (8 floats) per thread
    if (i >= n4) return;
    const float4* fp = (const float4*)f;
    float4 a = fp[i * 2], b = fp[i * 2 + 1];
    uint4 r;
    r.x = pack2bf(a.x, a.y); r.y = pack2bf(a.z, a.w);
    r.z = pack2bf(b.x, b.y); r.w = pack2bf(b.z, b.w);
    ((uint4*)o)[i] = r;
}

// ---- weight (OUT_C, C, 1, 4) fp32 -> Bt[o][kk*128 + c] bf16 ----
__global__ void wconv_kernel(const float* __restrict__ w, unsigned short* __restrict__ bt) {
    int i = blockIdx.x * 256 + threadIdx.x;
    if (i >= COUT * CIN) return;
    int o = i >> 7, c = i & 127;
#pragma unroll
    for (int kk = 0; kk < 4; ++kk)
        bt[o * KGEMM + kk * CIN + c] = f2bf(w[(o * CIN + c) * 4 + kk]);
}

// Build fc0..fc3 for 8 channels (one uint4 = 8 bf16) and store 4x uint4 to LDS row.
__device__ __forceinline__ void compute_store(const uint4 n[6], unsigned short* rowp, int c8) {
    unsigned o1[4], o2[4], o3[4];
#pragma unroll
    for (int w = 0; w < 4; ++w) {
        float xl[6], xh[6];
#pragma unroll
        for (int j = 0; j < 6; ++j) {
            unsigned uw = ((const unsigned*)&n[j])[w];
            xl[j] = bf_lo(uw); xh[j] = bf_hi(uw);
        }
        float f1l = xl[1] + xl[2] + xl[3] + xl[4] + xl[5];
        float f1h = xh[1] + xh[2] + xh[3] + xh[4] + xh[5];
        float f2l = fabsf(5.0f * xl[0] - f1l);
        float f2h = fabsf(5.0f * xh[0] - f1h);
        float f3l = 0.f, f3h = 0.f;
#pragma unroll
        for (int a = 1; a < 5; ++a)
#pragma unroll
            for (int b = a + 1; b < 6; ++b) {
                f3l += fabsf(xl[a] - xl[b]);
                f3h += fabsf(xh[a] - xh[b]);
            }
        o1[w] = pack2bf(f1l, f1h); o2[w] = pack2bf(f2l, f2h); o3[w] = pack2bf(f3l, f3h);
    }
    *(uint4*)&rowp[0 * 128 + c8 * 8] = n[0];
    *(uint4*)&rowp[1 * 128 + c8 * 8] = *(uint4*)o1;
    *(uint4*)&rowp[2 * 128 + c8 * 8] = *(uint4*)o2;
    *(uint4*)&rowp[3 * 128 + c8 * 8] = *(uint4*)o3;
}

__global__ __launch_bounds__(256, 4)
void meshconv_fast(const unsigned* __restrict__ featbf,
                   const int* __restrict__ ring,
                   const unsigned short* __restrict__ wbt,
                   const float* __restrict__ bias,
                   float* __restrict__ out)
{
    __shared__ unsigned short fcv[MBLK * LDF];
    __shared__ int ridx[MBLK * 6];

    const int t = threadIdx.x;
    // batch-per-XCD swizzle: XCD x gets blocks [x*512, (x+1)*512) = batch x
    const int bid = (blockIdx.x & 7) * (GRID / 8) + (blockIdx.x >> 3);
    const int base = bid * MBLK;
    const int batch = base >> 14;

    if (t < 48)  // 32 faces * 6 ints = 48 uint4
        ((uint4*)ridx)[t] = ((const uint4*)(ring + (size_t)base * 6))[t];
    __syncthreads();

    // ---- phase 1: 16 faces per pass, 8 channels per thread, all 12 gathers in flight ----
    {
        const int c8 = t & 15;   // channel octet [8*c8, 8*c8+8)
        const int fq = t >> 4;   // face within pass
        const uint4* __restrict__ fb = (const uint4*)featbf + (size_t)batch * NFACE * 16;
        const int* r0 = &ridx[fq * 6];
        const int* r1 = &ridx[(16 + fq) * 6];
        uint4 na[6], nb[6];
#pragma unroll
        for (int j = 0; j < 6; ++j) na[j] = fb[(size_t)r0[j] * 16 + c8];
#pragma unroll
        for (int j = 0; j < 6; ++j) nb[j] = fb[(size_t)r1[j] * 16 + c8];
        compute_store(na, &fcv[fq * LDF], c8);
        compute_store(nb, &fcv[(16 + fq) * LDF], c8);
    }
    __syncthreads();

    // ---- phase 2: MFMA GEMM  [32 x 512] x [512 x 128] ----
    const int w  = t >> 6;   // wave 0..3 -> cols [32w, 32w+32)
    const int l  = t & 63;
    const int lo = l & 15;
    const int hi = l >> 4;
    const int col0 = w * 32;

    f32x4 acc[2][2];
#pragma unroll
    for (int rt = 0; rt < 2; ++rt)
#pragma unroll
        for (int ct = 0; ct < 2; ++ct)
            acc[rt][ct] = (f32x4){0.f, 0.f, 0.f, 0.f};

    const unsigned short* __restrict__ wb0 = wbt + (size_t)(col0 + lo) * KGEMM;

    for (int ks = 0; ks < 16; ++ks) {
        const int k0 = ks * 32 + hi * 8;
        short8 a0 = *(const short8*)&fcv[(0 * 16 + lo) * LDF + k0];
        short8 a1 = *(const short8*)&fcv[(1 * 16 + lo) * LDF + k0];
        short8 b0 = *(const short8*)&wb0[k0];
        short8 b1 = *(const short8*)&wb0[16 * KGEMM + k0];

        acc[0][0] = __builtin_amdgcn_mfma_f32_16x16x32_bf16(a0, b0, acc[0][0], 0, 0, 0);
        acc[1][0] = __builtin_amdgcn_mfma_f32_16x16x32_bf16(a1, b0, acc[1][0], 0, 0, 0);
        acc[0][1] = __builtin_amdgcn_mfma_f32_16x16x32_bf16(a0, b1, acc[0][1], 0, 0, 0);
        acc[1][1] = __builtin_amdgcn_mfma_f32_16x16x32_bf16(a1, b1, acc[1][1], 0, 0, 0);
    }

    // ---- epilogue: + bias, store fp32 ----
    const float bo0 = bias[col0 + lo];
    const float bo1 = bias[col0 + 16 + lo];
#pragma unroll
    for (int rt = 0; rt < 2; ++rt) {
#pragma unroll
        for (int v = 0; v < 4; ++v) {
            const int r = base + rt * 16 + hi * 4 + v;  // C/D: row=(l>>4)*4+v, col=l&15  [m89]
            out[(size_t)r * COUT + col0 + lo]      = acc[rt][0][v] + bo0;
            out[(size_t)r * COUT + col0 + 16 + lo] = acc[rt][1][v] + bo1;
        }
    }
}

// fallback (ws too small for bf16 feature copy): fp32 gather version (R2 structure)
__global__ __launch_bounds__(256, 4)
void meshconv_ref(const float* __restrict__ feat,
                  const int* __restrict__ ring,
                  const unsigned short* __restrict__ wbt,
                  const float* __restrict__ bias,
                  float* __restrict__ out)
{
    __shared__ unsigned short fcv[MBLK * LDF];
    __shared__ int ridx[MBLK * 6];

    const int t = threadIdx.x;
    const int bid = (blockIdx.x & 7) * (GRID / 8) + (blockIdx.x >> 3);
    const int base = bid * MBLK;
    const int batch = base >> 14;

    for (int i = t; i < MBLK * 6; i += 256)
        ridx[i] = ring[(size_t)base * 6 + i];
    __syncthreads();

    {
        const int c2 = t & 63;
        const int fq = t >> 6;
        const float2* fb = (const float2*)feat + (size_t)batch * NFACE * 64;
        for (int it = 0; it < MBLK / 4; ++it) {
            const int fl = it * 4 + fq;
            const int* ri = &ridx[fl * 6];
            float nl[6], nh[6];
#pragma unroll
            for (int j = 0; j < 6; ++j) {
                float2 u = fb[(size_t)ri[j] * 64 + c2];
                nl[j] = u.x; nh[j] = u.y;
            }
            float fc1l = nl[1] + nl[2] + nl[3] + nl[4] + nl[5];
            float fc1h = nh[1] + nh[2] + nh[3] + nh[4] + nh[5];
            float fc2l = fabsf(5.0f * nl[0] - fc1l);
            float fc2h = fabsf(5.0f * nh[0] - fc1h);
            float fc3l = 0.f, fc3h = 0.f;
#pragma unroll
            for (int a = 1; a < 5; ++a)
#pragma unroll
                for (int b = a + 1; b < 6; ++b) {
                    fc3l += fabsf(nl[a] - nl[b]);
                    fc3h += fabsf(nh[a] - nh[b]);
                }
            unsigned* row = (unsigned*)&fcv[fl * LDF];
            row[c2]       = pack2bf(nl[0], nh[0]);
            row[64 + c2]  = pack2bf(fc1l, fc1h);
            row[128 + c2] = pack2bf(fc2l, fc2h);
            row[192 + c2] = pack2bf(fc3l, fc3h);
        }
    }
    __syncthreads();

    const int w  = t >> 6;
    const int l  = t & 63;
    const int lo = l & 15;
    const int hi = l >> 4;
    const int col0 = w * 32;

    f32x4 acc[2][2];
#pragma unroll
    for (int rt = 0; rt < 2; ++rt)
#pragma unroll
        for (int ct = 0; ct < 2; ++ct)
            acc[rt][ct] = (f32x4){0.f, 0.f, 0.f, 0.f};

    const unsigned short* __restrict__ wb0 = wbt + (size_t)(col0 + lo) * KGEMM;

    for (int ks = 0; ks < 16; ++ks) {
        const int k0 = ks * 32 + hi * 8;
        short8 a0 = *(const short8*)&fcv[(0 * 16 + lo) * LDF + k0];
        short8 a1 = *(const short8*)&fcv[(1 * 16 + lo) * LDF + k0];
        short8 b0 = *(const short8*)&wb0[k0];
        short8 b1 = *(const short8*)&wb0[16 * KGEMM + k0];
        acc[0][0] = __builtin_amdgcn_mfma_f32_16x16x32_bf16(a0, b0, acc[0][0], 0, 0, 0);
        acc[1][0] = __builtin_amdgcn_mfma_f32_16x16x32_bf16(a1, b0, acc[1][0], 0, 0, 0);
        acc[0][1] = __builtin_amdgcn_mfma_f32_16x16x32_bf16(a0, b1, acc[0][1], 0, 0, 0);
        acc[1][1] = __builtin_amdgcn_mfma_f32_16x16x32_bf16(a1, b1, acc[1][1], 0, 0, 0);
    }

    const float bo0 = bias[col0 + lo];
    const float bo1 = bias[col0 + 16 + lo];
#pragma unroll
    for (int rt = 0; rt < 2; ++rt) {
#pragma unroll
        for (int v = 0; v < 4; ++v) {
            const int r = base + rt * 16 + hi * 4 + v;
            out[(size_t)r * COUT + col0 + lo]      = acc[rt][0][v] + bo0;
            out[(size_t)r * COUT + col0 + 16 + lo] = acc[rt][1][v] + bo1;
        }
    }
}

__global__ void zero_kernel(const int* __restrict__ zm, const int* __restrict__ zf,
                            float* __restrict__ out) {
    const int i = blockIdx.x;
    const size_t face = (size_t)zm[i] * NFACE + zf[i];
    out[face * COUT + threadIdx.x] = 0.0f;
}

extern "C" void kernel_launch(void* const* d_in, const int* in_sizes, int n_in,
                              void* d_out, int out_size, void* d_ws, size_t ws_size,
                              hipStream_t stream) {
    const float* feat = (const float*)d_in[0];
    const int*   ring = (const int*)d_in[1];
    const float* wgt  = (const float*)d_in[2];
    const float* bias = (const float*)d_in[3];
    const int*   zm   = (const int*)d_in[4];
    const int*   zf   = (const int*)d_in[5];
    float* out = (float*)d_out;

    const size_t featbf_bytes = (size_t)NBATCH * NFACE * CIN * 2;  // 32 MiB
    const size_t wbt_bytes = (size_t)COUT * KGEMM * 2;             // 128 KiB
    const bool use_bf16 = ws_size >= featbf_bytes + wbt_bytes;

    if (use_bf16) {
        unsigned* featbf = (unsigned*)d_ws;
        unsigned short* wbt = (unsigned short*)((char*)d_ws + featbf_bytes);
        const int n4 = NBATCH * NFACE * CIN / 8;
        hipLaunchKernelGGL(fconv_kernel, dim3((n4 + 255) / 256), dim3(256), 0, stream,
                           feat, featbf, n4);
        hipLaunchKernelGGL(wconv_kernel, dim3((COUT * CIN + 255) / 256), dim3(256), 0, stream,
                           wgt, wbt);
        hipLaunchKernelGGL(meshconv_fast, dim3(GRID), dim3(256), 0, stream,
                           featbf, ring, wbt, bias, out);
    } else {
        unsigned short* wbt = (unsigned short*)d_ws;
        hipLaunchKernelGGL(wconv_kernel, dim3((COUT * CIN + 255) / 256), dim3(256), 0, stream,
                           wgt, wbt);
        hipLaunchKernelGGL(meshconv_ref, dim3(GRID), dim3(256), 0, stream,
                           feat, ring, wbt, bias, out);
    }
    hipLaunchKernelGGL(zero_kernel, dim3(1024), dim3(128), 0, stream, zm, zf, out);
}

// Round 4
// 65.724 us; speedup vs baseline: 1.5051x; 1.4662x over previous
//
#include <hip/hip_runtime.h>
#include <hip/hip_bf16.h>

typedef __attribute__((ext_vector_type(8))) short short8;
typedef __attribute__((ext_vector_type(4))) float f32x4;

#define NFACE 16384
#define NBATCH 8
#define CIN 128
#define COUT 128
#define KGEMM 512
#define MBLK 128                       // faces per block (v4)
#define GRID ((NBATCH * NFACE) / MBLK) // 1024, divisible by 8
#define LDW 136                        // W_lds row stride in shorts (128 + 8)
#define LDA 136                        // fcv row stride in shorts (128 + 8)

__device__ __forceinline__ unsigned short f2bf(float x) {
    union { float f; unsigned u; } v; v.f = x;
    unsigned r = v.u + 0x7fffu + ((v.u >> 16) & 1u);  // RNE
    return (unsigned short)(r >> 16);
}
__device__ __forceinline__ unsigned pack2bf(float lo, float hi) {
    return (unsigned)f2bf(lo) | ((unsigned)f2bf(hi) << 16);
}
__device__ __forceinline__ float bf_lo(unsigned u) { union { unsigned u; float f; } v; v.u = u << 16; return v.f; }
__device__ __forceinline__ float bf_hi(unsigned u) { union { unsigned u; float f; } v; v.u = u & 0xffff0000u; return v.f; }

// ---- features fp32 -> packed bf16 (uint = 2 channels) ----
__global__ void fconv_kernel(const float* __restrict__ f, unsigned* __restrict__ o, int n4) {
    int i = blockIdx.x * 256 + threadIdx.x;  // one uint4 (8 floats) per thread
    if (i >= n4) return;
    const float4* fp = (const float4*)f;
    float4 a = fp[i * 2], b = fp[i * 2 + 1];
    uint4 r;
    r.x = pack2bf(a.x, a.y); r.y = pack2bf(a.z, a.w);
    r.z = pack2bf(b.x, b.y); r.w = pack2bf(b.z, b.w);
    ((uint4*)o)[i] = r;
}

// ---- weight fp32 -> bf16, c-major K layout: bt2[o][c*4+kk] == contiguous convert ----
__global__ void wconv2_kernel(const float* __restrict__ w, unsigned short* __restrict__ bt2) {
    int i = blockIdx.x * 256 + threadIdx.x;  // one (o,c) pair = 4 floats
    if (i >= COUT * CIN) return;
    float4 wv = ((const float4*)w)[i];
    unsigned short s0 = f2bf(wv.x), s1 = f2bf(wv.y), s2 = f2bf(wv.z), s3 = f2bf(wv.w);
    uint2 p; p.x = (unsigned)s0 | ((unsigned)s1 << 16); p.y = (unsigned)s2 | ((unsigned)s3 << 16);
    ((uint2*)bt2)[i] = p;
}

// ---- old-layout weight (fallback path): bt[o][kk*128+c] ----
__global__ void wconv_kernel(const float* __restrict__ w, unsigned short* __restrict__ bt) {
    int i = blockIdx.x * 256 + threadIdx.x;
    if (i >= COUT * CIN) return;
    int o = i >> 7, c = i & 127;
#pragma unroll
    for (int kk = 0; kk < 4; ++kk)
        bt[o * KGEMM + kk * CIN + c] = f2bf(w[(o * CIN + c) * 4 + kk]);
}

__global__ __launch_bounds__(512, 2)
void meshconv_v4(const unsigned* __restrict__ featbf,
                 const int* __restrict__ ring,
                 const unsigned short* __restrict__ wbt2,
                 const float* __restrict__ bias,
                 float* __restrict__ out)
{
    __shared__ unsigned short Wl[COUT * LDW];   // 34.0 KiB: weight K-chunk
    __shared__ unsigned short Al[MBLK * LDA];   // 34.0 KiB: fcv K-chunk
    __shared__ int ridx[MBLK * 6];              // 3 KiB

    const int t = threadIdx.x;
    // batch-per-XCD swizzle: 128 blocks per batch, one batch per XCD
    const int bid = (blockIdx.x & 7) * (GRID / 8) + (blockIdx.x >> 3);
    const int base = bid * MBLK;
    const int batch = bid >> 7;

    if (t < 192)  // 128 faces * 6 ints = 192 uint4
        ((uint4*)ridx)[t] = ((const uint4*)(ring + (size_t)base * 6))[t];
    __syncthreads();

    // GEMM mapping: 8 waves = 4 face-tiles (32 faces) x 2 col-halves (64 cols)
    const int w  = t >> 6;
    const int l  = t & 63;
    const int lo = l & 15;
    const int hi = l >> 4;
    const int wr = w >> 1;   // face-tile 0..3
    const int wc = w & 1;    // col-half 0..1

    // phase-1 mapping: thread = (face fq, channel-octet c8 within chunk)
    const int fq = t >> 2;
    const int c8 = t & 3;
    const uint4* __restrict__ fb = (const uint4*)featbf + (size_t)(batch << 14) * 16;
    const int* ri = &ridx[fq * 6];

    f32x4 acc[2][4];
#pragma unroll
    for (int rt = 0; rt < 2; ++rt)
#pragma unroll
        for (int ct = 0; ct < 4; ++ct)
            acc[rt][ct] = (f32x4){0.f, 0.f, 0.f, 0.f};

    for (int ch = 0; ch < 4; ++ch) {
        if (ch) __syncthreads();  // WAR: previous GEMM reads done before overwrite

        // ---- stage weight K-chunk: cols 0..127 x K [ch*128, ch*128+128) ----
        {
            const int o = t >> 2, seg = t & 3;  // 64 B per thread
            const uint4* src = (const uint4*)(wbt2 + (size_t)o * KGEMM + ch * 128 + seg * 32);
            uint4* dst = (uint4*)&Wl[o * LDW + seg * 32];
            uint4 v0 = src[0], v1 = src[1], v2 = src[2], v3 = src[3];
            dst[0] = v0; dst[1] = v1; dst[2] = v2; dst[3] = v3;
        }

        // ---- gather 6 neighbor 16-B segments, build fcv chunk (8 channels) ----
        {
            uint4 n[6];
#pragma unroll
            for (int j = 0; j < 6; ++j)
                n[j] = fb[(size_t)ri[j] * 16 + ch * 4 + c8];

            unsigned ov[16];
#pragma unroll
            for (int q = 0; q < 4; ++q) {  // q = uint word = channels 2q, 2q+1
                float xl[6], xh[6];
                unsigned uw0;
#pragma unroll
                for (int j = 0; j < 6; ++j) {
                    unsigned uw = ((const unsigned*)&n[j])[q];
                    if (j == 0) uw0 = uw;
                    xl[j] = bf_lo(uw); xh[j] = bf_hi(uw);
                }
                float f1l = xl[1] + xl[2] + xl[3] + xl[4] + xl[5];
                float f1h = xh[1] + xh[2] + xh[3] + xh[4] + xh[5];
                float f2l = fabsf(5.0f * xl[0] - f1l);
                float f2h = fabsf(5.0f * xh[0] - f1h);
                float f3l = 0.f, f3h = 0.f;
#pragma unroll
                for (int a = 1; a < 5; ++a)
#pragma unroll
                    for (int b = a + 1; b < 6; ++b) {
                        f3l += fabsf(xl[a] - xl[b]);
                        f3h += fabsf(xh[a] - xh[b]);
                    }
                // K-local layout: channel c' = c8*8 + {2q, 2q+1}; K = c'*4 + kk
                ov[q * 4 + 0] = (uw0 & 0xffffu) | ((unsigned)f2bf(f1l) << 16);
                ov[q * 4 + 1] = (unsigned)f2bf(f2l) | ((unsigned)f2bf(f3l) << 16);
                ov[q * 4 + 2] = (uw0 >> 16) | ((unsigned)f2bf(f1h) << 16);
                ov[q * 4 + 3] = (unsigned)f2bf(f2h) | ((unsigned)f2bf(f3h) << 16);
            }
            uint4* dst = (uint4*)&Al[fq * LDA + c8 * 32];
#pragma unroll
            for (int q = 0; q < 4; ++q)
                dst[q] = (uint4){ov[q * 4 + 0], ov[q * 4 + 1], ov[q * 4 + 2], ov[q * 4 + 3]};
        }
        __syncthreads();

        // ---- GEMM on chunk: K=128 = 4 ksteps of 32 ----
#pragma unroll
        for (int ks = 0; ks < 4; ++ks) {
            const int k0 = ks * 32 + hi * 8;
            short8 a0 = *(const short8*)&Al[(wr * 32 + lo) * LDA + k0];
            short8 a1 = *(const short8*)&Al[(wr * 32 + 16 + lo) * LDA + k0];
#pragma unroll
            for (int ct = 0; ct < 4; ++ct) {
                short8 b = *(const short8*)&Wl[(wc * 64 + ct * 16 + lo) * LDW + k0];
                acc[0][ct] = __builtin_amdgcn_mfma_f32_16x16x32_bf16(a0, b, acc[0][ct], 0, 0, 0);
                acc[1][ct] = __builtin_amdgcn_mfma_f32_16x16x32_bf16(a1, b, acc[1][ct], 0, 0, 0);
            }
        }
    }

    // ---- epilogue: + bias, store fp32 ----
    const int col0 = wc * 64;
    float bo[4];
#pragma unroll
    for (int ct = 0; ct < 4; ++ct) bo[ct] = bias[col0 + ct * 16 + lo];
#pragma unroll
    for (int rt = 0; rt < 2; ++rt) {
#pragma unroll
        for (int ct = 0; ct < 4; ++ct) {
#pragma unroll
            for (int v = 0; v < 4; ++v) {
                const int r = base + wr * 32 + rt * 16 + hi * 4 + v;  // C/D: row=(l>>4)*4+v, col=l&15
                out[(size_t)r * COUT + col0 + ct * 16 + lo] = acc[rt][ct][v] + bo[ct];
            }
        }
    }
}

// fallback (ws too small for bf16 feature copy): fp32 gather, old weight layout
__global__ __launch_bounds__(256, 4)
void meshconv_ref(const float* __restrict__ feat,
                  const int* __restrict__ ring,
                  const unsigned short* __restrict__ wbt,
                  const float* __restrict__ bias,
                  float* __restrict__ out)
{
#define RMBLK 32
#define RLDF 520
    __shared__ unsigned short fcv[RMBLK * RLDF];
    __shared__ int ridx[RMBLK * 6];

    const int t = threadIdx.x;
    const int bid = (blockIdx.x & 7) * (4096 / 8) + (blockIdx.x >> 3);
    const int base = bid * RMBLK;
    const int batch = base >> 14;

    for (int i = t; i < RMBLK * 6; i += 256)
        ridx[i] = ring[(size_t)base * 6 + i];
    __syncthreads();

    {
        const int c2 = t & 63;
        const int fq = t >> 6;
        const float2* fb = (const float2*)feat + (size_t)batch * NFACE * 64;
        for (int it = 0; it < RMBLK / 4; ++it) {
            const int fl = it * 4 + fq;
            const int* ri = &ridx[fl * 6];
            float nl[6], nh[6];
#pragma unroll
            for (int j = 0; j < 6; ++j) {
                float2 u = fb[(size_t)ri[j] * 64 + c2];
                nl[j] = u.x; nh[j] = u.y;
            }
            float fc1l = nl[1] + nl[2] + nl[3] + nl[4] + nl[5];
            float fc1h = nh[1] + nh[2] + nh[3] + nh[4] + nh[5];
            float fc2l = fabsf(5.0f * nl[0] - fc1l);
            float fc2h = fabsf(5.0f * nh[0] - fc1h);
            float fc3l = 0.f, fc3h = 0.f;
#pragma unroll
            for (int a = 1; a < 5; ++a)
#pragma unroll
                for (int b = a + 1; b < 6; ++b) {
                    fc3l += fabsf(nl[a] - nl[b]);
                    fc3h += fabsf(nh[a] - nh[b]);
                }
            unsigned* row = (unsigned*)&fcv[fl * RLDF];
            row[c2]       = pack2bf(nl[0], nh[0]);
            row[64 + c2]  = pack2bf(fc1l, fc1h);
            row[128 + c2] = pack2bf(fc2l, fc2h);
            row[192 + c2] = pack2bf(fc3l, fc3h);
        }
    }
    __syncthreads();

    const int w  = t >> 6;
    const int l  = t & 63;
    const int lo = l & 15;
    const int hi = l >> 4;
    const int col0 = w * 32;

    f32x4 acc[2][2];
#pragma unroll
    for (int rt = 0; rt < 2; ++rt)
#pragma unroll
        for (int ct = 0; ct < 2; ++ct)
            acc[rt][ct] = (f32x4){0.f, 0.f, 0.f, 0.f};

    const unsigned short* __restrict__ wb0 = wbt + (size_t)(col0 + lo) * KGEMM;

    for (int ks = 0; ks < 16; ++ks) {
        const int k0 = ks * 32 + hi * 8;
        short8 a0 = *(const short8*)&fcv[(0 * 16 + lo) * RLDF + k0];
        short8 a1 = *(const short8*)&fcv[(1 * 16 + lo) * RLDF + k0];
        short8 b0 = *(const short8*)&wb0[k0];
        short8 b1 = *(const short8*)&wb0[16 * KGEMM + k0];
        acc[0][0] = __builtin_amdgcn_mfma_f32_16x16x32_bf16(a0, b0, acc[0][0], 0, 0, 0);
        acc[1][0] = __builtin_amdgcn_mfma_f32_16x16x32_bf16(a1, b0, acc[1][0], 0, 0, 0);
        acc[0][1] = __builtin_amdgcn_mfma_f32_16x16x32_bf16(a0, b1, acc[0][1], 0, 0, 0);
        acc[1][1] = __builtin_amdgcn_mfma_f32_16x16x32_bf16(a1, b1, acc[1][1], 0, 0, 0);
    }

    const float bo0 = bias[col0 + lo];
    const float bo1 = bias[col0 + 16 + lo];
#pragma unroll
    for (int rt = 0; rt < 2; ++rt) {
#pragma unroll
        for (int v = 0; v < 4; ++v) {
            const int r = base + rt * 16 + hi * 4 + v;
            out[(size_t)r * COUT + col0 + lo]      = acc[rt][0][v] + bo0;
            out[(size_t)r * COUT + col0 + 16 + lo] = acc[rt][1][v] + bo1;
        }
    }
}

__global__ void zero_kernel(const int* __restrict__ zm, const int* __restrict__ zf,
                            float* __restrict__ out) {
    const int i = blockIdx.x;
    const size_t face = (size_t)zm[i] * NFACE + zf[i];
    out[face * COUT + threadIdx.x] = 0.0f;
}

extern "C" void kernel_launch(void* const* d_in, const int* in_sizes, int n_in,
                              void* d_out, int out_size, void* d_ws, size_t ws_size,
                              hipStream_t stream) {
    const float* feat = (const float*)d_in[0];
    const int*   ring = (const int*)d_in[1];
    const float* wgt  = (const float*)d_in[2];
    const float* bias = (const float*)d_in[3];
    const int*   zm   = (const int*)d_in[4];
    const int*   zf   = (const int*)d_in[5];
    float* out = (float*)d_out;

    const size_t featbf_bytes = (size_t)NBATCH * NFACE * CIN * 2;  // 32 MiB
    const size_t wbt_bytes = (size_t)COUT * KGEMM * 2;             // 128 KiB
    const bool use_bf16 = ws_size >= featbf_bytes + wbt_bytes;

    if (use_bf16) {
        unsigned* featbf = (unsigned*)d_ws;
        unsigned short* wbt2 = (unsigned short*)((char*)d_ws + featbf_bytes);
        const int n4 = NBATCH * NFACE * CIN / 8;
        hipLaunchKernelGGL(fconv_kernel, dim3((n4 + 255) / 256), dim3(256), 0, stream,
                           feat, featbf, n4);
        hipLaunchKernelGGL(wconv2_kernel, dim3((COUT * CIN + 255) / 256), dim3(256), 0, stream,
                           wgt, wbt2);
        hipLaunchKernelGGL(meshconv_v4, dim3(GRID), dim3(512), 0, stream,
                           featbf, ring, wbt2, bias, out);
    } else {
        unsigned short* wbt = (unsigned short*)d_ws;
        hipLaunchKernelGGL(wconv_kernel, dim3((COUT * CIN + 255) / 256), dim3(256), 0, stream,
                           wgt, wbt);
        hipLaunchKernelGGL(meshconv_ref, dim3(4096), dim3(256), 0, stream,
                           feat, ring, wbt, bias, out);
    }
    hipLaunchKernelGGL(zero_kernel, dim3(1024), dim3(128), 0, stream, zm, zf, out);
}